// Round 15
// baseline (134.052 us; speedup 1.0000x reference)
//
#include <hip/hip_runtime.h>

typedef float v4f __attribute__((ext_vector_type(4)));

// frame classifier, m compile-time after unroll
__device__ __forceinline__ void addElem(int m, float v, float& a0, float& a1, float& a2) {
    if (m < 25) a0 += v; else if (m < 50) a1 += v; else a2 += v;
}

// A: lane = channel. Read 75 floats (PRE scalars | 18 f4 | 3-PRE scalars), 3 frame sums.
template<int PRE>
__device__ __forceinline__ void aPhase(const float* __restrict__ row, float* xb2, int c) {
    float a0 = 0.f, a1 = 0.f, a2 = 0.f;
    #pragma unroll
    for (int m = 0; m < PRE; ++m) a0 += row[m];              // PRE<=3 -> frame 0
    const v4f* p = (const v4f*)(row + PRE);                  // aligned by construction
    #pragma unroll
    for (int k = 0; k < 18; ++k) {
        v4f v = p[k];
        const int m0 = PRE + 4 * k;
        addElem(m0 + 0, v.x, a0, a1, a2);
        addElem(m0 + 1, v.y, a0, a1, a2);
        addElem(m0 + 2, v.z, a0, a1, a2);
        addElem(m0 + 3, v.w, a0, a1, a2);
    }
    #pragma unroll
    for (int m = PRE + 72; m < 75; ++m) a2 += row[m];        // frame 2
    xb2[0 * 256 + c] = a0; xb2[1 * 256 + c] = a1; xb2[2 * 256 + c] = a2;
}

// C: 256 lanes stream the segment densely from cache, gate, NT-store.
template<int I>   // PRE == I for quarter-aligned segments
__device__ __forceinline__ void cPhase(const float* __restrict__ xn, float* __restrict__ on,
                                       const float* gs, unsigned q, int ctid) {
    constexpr int PRE  = I;
    constexpr int OFF4 = (I * 75 + PRE) / 4;
    const v4f* x4 = (const v4f*)xn;
    v4f*       o4 = (v4f*)on;
    const unsigned b4 = q * 75u + (unsigned)OFF4;            // + c*300 + k
    #pragma unroll 3
    for (int it = 0; it < 18; ++it) {
        int j = it * 256 + ctid;
        unsigned c = ((unsigned)j * 3641u) >> 16;            // j/18, exact j<4608
        int k = j - (int)c * 18;
        unsigned idx = b4 + c * 300u + (unsigned)k;
        v4f v = x4[idx];
        int m0  = PRE + 4 * k;
        int t0  = (m0 * 41) >> 10;                           // m0/25
        int t3  = ((m0 + 3) * 41) >> 10;
        int rem = m0 - t0 * 25;
        float g0 = gs[c * 3 + t0];
        float g3 = gs[c * 3 + t3];
        v4f ov;
        ov.x = v.x * g0;
        ov.y = v.y * ((rem + 1 < 25) ? g0 : g3);
        ov.z = v.z * ((rem + 2 < 25) ? g0 : g3);
        ov.w = v.w * ((rem + 3 < 25) ? g0 : g3);
        __builtin_nontemporal_store(ov, &o4[idx]);
    }
    #pragma unroll
    for (int it = 0; it < 3; ++it) {                         // 3 edge scalars per channel
        int j = it * 256 + ctid;
        unsigned c = ((unsigned)j * 683u) >> 11;             // j/3, exact j<768
        int e = j - (int)c * 3;
        int m = (e < PRE) ? e : (72 + e);
        int t = (e < PRE) ? 0 : 2;
        unsigned fi = c * 1200u + (q * 4u + I) * 75u + (unsigned)m;
        float val = xn[fi] * gs[c * 3 + t];
        __builtin_nontemporal_store(val, &on[fi]);
    }
}

// Block = (n, quarter) = 4 segments, software-pipelined:
//   A(0); for i in 0..3: { B(i); [waves4-7: A(i+1)] || [waves0-3: C(i)]; }
// During every long slot the HBM read stream (A) and write stream (C) are
// BOTH active -> m13 mixed-copy regime. C re-reads x us after A read it -> L3 hit.
__global__ __launch_bounds__(512, 4) void k_pipe2(
    const float* __restrict__ x,
    const float* __restrict__ wsq, const float* __restrict__ bsq,
    const float* __restrict__ gamma, const float* __restrict__ beta,
    const float* __restrict__ rmean, const float* __restrict__ rvar,
    const float* __restrict__ wc1, const float* __restrict__ bc1,
    const float* __restrict__ wex, const float* __restrict__ bex,
    float* __restrict__ out)
{
    __shared__ float xb2[768];   // frame sums [t][c]
    __shared__ float gs[768];    // gate [c][t]
    __shared__ float part[384];  // squeeze partials
    __shared__ float ybn[48], y1[48], mv[48];

    const int tid = threadIdx.x;
    const int wv  = tid >> 6, ln = tid & 63;
    const unsigned bid = blockIdx.x;
    const unsigned u = (bid & 7u) * 64u + (bid >> 3);        // XCD chunk swizzle
    const unsigned n = u >> 2;
    const unsigned q = u & 3u;

    const float* xn = x   + (size_t)n * 307200u;
    float*       on = out + (size_t)n * 307200u;
    const int ca = (wv >= 4) ? ((wv - 4) * 64 + ln) : 0;     // A-wave channel
    const int ct = wv * 64 + ln;                             // C-wave lane id (0..255)

    auto bPhase = [&]() {
        if (tid < 384) {                                     // B1: squeeze partials
            int g = tid & 7, qq = tid >> 3;                  // qq 0..47
            int t = qq >> 4, r = qq & 15;
            float acc = 0.f;
            #pragma unroll 8
            for (int i2 = 0; i2 < 32; ++i2) {
                int c = i2 * 8 + g;                          // interleaved: bank-clean
                acc += xb2[t * 256 + c] * wsq[r * 256 + c];
            }
            part[tid] = acc;
        }
        __syncthreads();
        if (tid < 48) {                                      // combine+BN, conv1, diff (1 wave)
            int t = tid >> 4, r = tid & 15;
            float acc = 0.f;
            #pragma unroll
            for (int g = 0; g < 8; ++g) acc += part[(t * 16 + r) * 8 + g];
            float sc = gamma[r] * rsqrtf(rvar[r] + 1e-5f);
            ybn[t * 16 + r] = acc * (0.04f * sc) + (bsq[r] * sc + beta[r] - rmean[r] * sc);
            float yv = bc1[r];
            #pragma unroll
            for (int rr = 0; rr < 16; ++rr) yv += ybn[t * 16 + rr] * wc1[r * 16 + rr];
            y1[t * 16 + r] = yv;
            mv[t * 16 + r] = (t < 2) ? (y1[(t + 1) * 16 + r] - ybn[t * 16 + r]) : 0.f;
        }
        __syncthreads();
        {                                                    // B4: expand + sigmoid
            int c = tid & 255;
            float be = bex[c];
            if (tid < 256) {
                float a0 = be, a1 = be;
                #pragma unroll
                for (int r = 0; r < 16; ++r) {
                    float w = wex[c * 16 + r];
                    a0 += mv[r] * w; a1 += mv[16 + r] * w;
                }
                gs[c * 3 + 0] = 1.f / (1.f + expf(-a0));
                gs[c * 3 + 1] = 1.f / (1.f + expf(-a1));
            } else {
                float a2 = be;
                #pragma unroll
                for (int r = 0; r < 16; ++r) a2 += mv[32 + r] * wex[c * 16 + r];
                gs[c * 3 + 2] = 1.f / (1.f + expf(-a2));
            }
        }
        __syncthreads();
    };

    // ---- prologue: A(0) ----
    if (wv >= 4) aPhase<0>(xn + ca * 1200 + (q * 4 + 0) * 75, xb2, ca);
    __syncthreads();

    // ---- pipeline ----
    bPhase();                                                // B(0)
    if (wv >= 4) aPhase<1>(xn + ca * 1200 + (q * 4 + 1) * 75, xb2, ca);
    else         cPhase<0>(xn, on, gs, q, ct);
    __syncthreads();

    bPhase();                                                // B(1)
    if (wv >= 4) aPhase<2>(xn + ca * 1200 + (q * 4 + 2) * 75, xb2, ca);
    else         cPhase<1>(xn, on, gs, q, ct);
    __syncthreads();

    bPhase();                                                // B(2)
    if (wv >= 4) aPhase<3>(xn + ca * 1200 + (q * 4 + 3) * 75, xb2, ca);
    else         cPhase<2>(xn, on, gs, q, ct);
    __syncthreads();

    bPhase();                                                // B(3)
    if (wv < 4) cPhase<3>(xn, on, gs, q, ct);
}

extern "C" void kernel_launch(void* const* d_in, const int* in_sizes, int n_in,
                              void* d_out, int out_size, void* d_ws, size_t ws_size,
                              hipStream_t stream) {
    const float* x     = (const float*)d_in[0];
    const float* wsq   = (const float*)d_in[1];
    const float* bsq   = (const float*)d_in[2];
    const float* gamma = (const float*)d_in[3];
    const float* beta  = (const float*)d_in[4];
    const float* rmean = (const float*)d_in[5];
    const float* rvar  = (const float*)d_in[6];
    const float* wc1   = (const float*)d_in[7];
    const float* bc1   = (const float*)d_in[8];
    const float* wex   = (const float*)d_in[9];
    const float* bex   = (const float*)d_in[10];

    k_pipe2<<<512, 512, 0, stream>>>(x, wsq, bsq, gamma, beta,
                                     rmean, rvar, wc1, bc1, wex, bex,
                                     (float*)d_out);
}